// Round 13
// baseline (52.717 us; speedup 1.0000x reference)
//
#include <hip/hip_runtime.h>
#include <stdint.h>

// ---------------------------------------------------------------------------
// FractalLinear: IFS chaos game (JAX threefry-exact) + bilinear gather/scatter
// Round 13 = round-12 persistent pipelined apply + FULL upfront gather:
//   all kRPB=4 rows' scattered loads issue before the row loop (8 loads in
//   flight per thread vs 2), so each row's scatter never waits full HBM
//   latency -- the compiler's per-thread vmcnt(N) waits release row r while
//   rows r+1.. stay in flight. Same grid (512x1024), same 32KB LDS (2
//   blocks/CU), same LDS-only barriers (no vmcnt drain in the loop).
// Evidence trail: R4 46.5 -> R12 42.3 (pipelining real); sort (R10),
// hot-atomics (R8), CSR/compact/split restructures (R7/R9/R11) all dead.
// Fetch floor is 51MB unique scattered lines + 64MB stream write.
// ---------------------------------------------------------------------------
#ifndef PRNG_PARTITIONABLE
#define PRNG_PARTITIONABLE 1
#endif

namespace {

constexpr int kH  = 8192;
constexpr int kW  = 16384;
constexpr int kNT = 8;
constexpr int kNP = 1000;
constexpr int kCI = 10;
constexpr int kRPB = 4;          // rows per apply block (all gathered upfront)

typedef float floatx4 __attribute__((ext_vector_type(4)));  // nontemporal-OK

// Raw barrier: wait only on LDS ops, leave global loads/stores in flight.
// (__syncthreads emits s_waitcnt vmcnt(0) lgkmcnt(0) before s_barrier,
// which would drain the gather/store pipeline every iteration.)
#define BAR_LDS() asm volatile("s_waitcnt lgkmcnt(0)\n\ts_barrier" ::: "memory")

__device__ __forceinline__ uint32_t rotl32(uint32_t x, int n) {
  return (x << n) | (x >> (32 - n));
}

// Threefry-2x32, 20 rounds (Random123 / JAX convention).
__device__ void threefry2x32(uint32_t k0, uint32_t k1, uint32_t c0, uint32_t c1,
                             uint32_t& o0, uint32_t& o1) {
  const uint32_t ks2 = k0 ^ k1 ^ 0x1BD11BDAu;
  uint32_t x0 = c0 + k0, x1 = c1 + k1;
#define TF_R(r) { x0 += x1; x1 = rotl32(x1, (r)); x1 ^= x0; }
  TF_R(13) TF_R(15) TF_R(26) TF_R(6)
  x0 += k1;  x1 += ks2 + 1u;
  TF_R(17) TF_R(29) TF_R(16) TF_R(24)
  x0 += ks2; x1 += k0 + 2u;
  TF_R(13) TF_R(15) TF_R(26) TF_R(6)
  x0 += k0;  x1 += k1 + 3u;
  TF_R(17) TF_R(29) TF_R(16) TF_R(24)
  x0 += k1;  x1 += ks2 + 4u;
  TF_R(13) TF_R(15) TF_R(26) TF_R(6)
  x0 += ks2; x1 += k0 + 5u;
#undef TF_R
  o0 = x0; o1 = x1;
}

__device__ __forceinline__ uint32_t random_bits32(uint32_t k0, uint32_t k1,
                                                  uint32_t i, uint32_t size) {
#if PRNG_PARTITIONABLE
  uint32_t o0, o1;
  threefry2x32(k0, k1, 0u /* hi(i) */, i, o0, o1);
  (void)size;
  return o0 ^ o1;
#else
  const uint32_t half = size / 2u;
  const uint32_t j = (i < half) ? i : (i - half);
  uint32_t o0, o1;
  threefry2x32(k0, k1, j, j + half, o0, o1);
  return (i < half) ? o0 : o1;
#endif
}

__device__ __forceinline__ float u01(uint32_t bits) {
  return __uint_as_float((bits >> 9) | 0x3f800000u) - 1.0f;
}

// x86 cvttss2si semantics: out-of-range / NaN -> INT_MIN (matches CPU-ref).
__device__ __forceinline__ int cvt_f32_i32_x86(float v) {
  if (!(v >= -2147483648.0f && v < 2147483648.0f)) return (int)0x80000000;
  return (int)v;
}

// ---------------------------------------------------------------------------
// Kernel 1: chaos game, 8 lanes per point (one transform each).
// ---------------------------------------------------------------------------
__global__ __launch_bounds__(256) void fractal_chaos(
    const float* __restrict__ dna, int4* __restrict__ rec) {
  const int gid  = blockIdx.x * blockDim.x + threadIdx.x;
  const int n    = gid >> 3;
  const int lane = gid & 7;
  if (n >= kNP) return;

  uint32_t kp0, kp1, kg0, kg1;
#if PRNG_PARTITIONABLE
  threefry2x32(0u, 1u, 0u, 0u, kp0, kp1);
  threefry2x32(0u, 1u, 0u, 1u, kg0, kg1);
#else
  uint32_t a0, a1, b0, b1;
  threefry2x32(0u, 1u, 0u, 2u, a0, a1);
  threefry2x32(0u, 1u, 1u, 3u, b0, b1);
  kp0 = a0; kp1 = b0; kg0 = a1; kg1 = b1;
#endif

  const float A  = dna[lane * 7 + 0], Bb = dna[lane * 7 + 1];
  const float C  = dna[lane * 7 + 2], D  = dna[lane * 7 + 3];
  const float E  = dna[lane * 7 + 4], F  = dna[lane * 7 + 5];
  const float P  = dna[lane * 7 + 6];

  float z[kCI];
  #pragma unroll
  for (int i = 0; i < kCI; ++i) {
    uint32_t ki0, ki1;
    threefry2x32(kg0, kg1, 0u, (uint32_t)i, ki0, ki1);   // fold_in(kg, i)
    const uint32_t bb = random_bits32(ki0, ki1, (uint32_t)(n * kNT + lane),
                                      (uint32_t)(kNP * kNT));
    const float u = fmaxf(u01(bb), 1.17549435e-38f);
    const float g = -logf(-logf(u));
    z[i] = P + g;
  }

  const uint32_t bx = random_bits32(kp0, kp1, (uint32_t)(2 * n),     2u * kNP);
  const uint32_t by = random_bits32(kp0, kp1, (uint32_t)(2 * n + 1), 2u * kNP);
  float px = u01(bx) * 2.0f - 1.0f;
  float py = u01(by) * 2.0f - 1.0f;

  #pragma unroll
  for (int i = 0; i < kCI; ++i) {
    // argmax over the 8 lanes, first-index tiebreak (matches jnp.argmax)
    float zb = z[i];
    int   bt = lane;
    #pragma unroll
    for (int m = 1; m < 8; m <<= 1) {
      const float zo = __shfl_xor(zb, m, 8);
      const int   to = __shfl_xor(bt, m, 8);
      if (zo > zb || (zo == zb && to < bt)) { zb = zo; bt = to; }
    }
    const float A_ = __shfl(A,  bt, 8), B_ = __shfl(Bb, bt, 8);
    const float C_ = __shfl(C,  bt, 8), D_ = __shfl(D,  bt, 8);
    const float E_ = __shfl(E,  bt, 8), F_ = __shfl(F,  bt, 8);
    const float nx = A_ * px + B_ * py + E_;
    const float ny = C_ * px + D_ * py + F_;
    px = nx; py = ny;
  }

  if (lane == 0) {
    const float xc = ((px + 1.0f) * 0.5f) * (float)(kW - 1);
    const float yc = ((py + 1.0f) * 0.5f) * (float)(kH - 1);
    int xl = cvt_f32_i32_x86(floorf(xc));
    int yl = cvt_f32_i32_x86(floorf(yc));
    xl = min(max(xl, 0), kW - 2);
    yl = min(max(yl, 0), kH - 2);
    const float xw = xc - (float)xl;   // NOT clipped (matches reference)
    const float yw = yc - (float)yl;
    rec[n] = make_int4(xl, __float_as_int(xw), yl, __float_as_int(yw));
  }
}

// ---------------------------------------------------------------------------
// Kernel 2: persistent pipelined apply, full upfront gather.
// 512 blocks x 1024 thr, 4 rows each. All 8 gather loads per thread issue
// before the row loop; per row: scatter (vmcnt releases oldest pair) ->
// LDS-barrier -> epilogue (acc+bias, NT store, fused re-zero) -> LDS-barrier.
// ---------------------------------------------------------------------------
__global__ __launch_bounds__(1024) void fractal_apply(
    const float* __restrict__ x, const float* __restrict__ bias,
    const int4* __restrict__ rec, float* __restrict__ out, int B) {
  __shared__ __align__(16) float acc[kH];        // 32 KB -> 2 blocks/CU
  const int tid = threadIdx.x;
  const int r0  = blockIdx.x * kRPB;

  // per-thread point record (threads 0..999)
  const bool hav = tid < kNP;
  int xl = 0, yl = 0;
  float xw = 0.f, yw = 0.f;
  if (hav) {
    const int4 rr = rec[tid];
    xl = rr.x; xw = __int_as_float(rr.y);
    yl = rr.z; yw = __int_as_float(rr.w);
  }
  const float xw0 = 1.0f - xw;
  const float w0  = 1.0f - yw;

  // issue ALL rows' gather loads upfront (8 in flight per thread)
  float v0[kRPB], v1[kRPB];
  if (hav) {
    const float* xp = x + (size_t)r0 * kW + xl;
    #pragma unroll
    for (int it = 0; it < kRPB; ++it) {
      if (r0 + it < B) {
        v0[it] = xp[(size_t)it * kW];
        v1[it] = xp[(size_t)it * kW + 1];
      }
    }
  }

  // zero acc (overlaps the gathers)
  float4* acc4 = reinterpret_cast<float4*>(acc);
  acc4[tid]        = make_float4(0.f, 0.f, 0.f, 0.f);
  acc4[tid + 1024] = make_float4(0.f, 0.f, 0.f, 0.f);

  BAR_LDS();   // zeros visible; gather loads stay in flight

  const floatx4* __restrict__ bias4 = reinterpret_cast<const floatx4*>(bias);

  #pragma unroll
  for (int it = 0; it < kRPB; ++it) {
    const int r = r0 + it;
    if (r >= B) break;                        // block-uniform, barrier-safe

    // scatter current row (vmcnt wait covers only this row's pair)
    if (hav) {
      const float xv = v0[it] * xw0 + v1[it] * xw;
      atomicAdd(&acc[yl],     xv * w0);
      atomicAdd(&acc[yl + 1], xv * yw);
    }

    BAR_LDS();   // all scatters done (lgkmcnt only; VMEM still in flight)

    // epilogue: out = acc/1000 + bias, then zero acc for the next row
    float* __restrict__ outrow = out + (size_t)r * kH;
    floatx4* __restrict__ out4 = reinterpret_cast<floatx4*>(outrow);
    #pragma unroll
    for (int j = 0; j < 2; ++j) {
      const int g = tid + j * 1024;
      const float4 a  = acc4[g];
      const floatx4 bi = bias4[g];
      floatx4 o;
      o.x = a.x / 1000.0f + bi.x;
      o.y = a.y / 1000.0f + bi.y;
      o.z = a.z / 1000.0f + bi.z;
      o.w = a.w / 1000.0f + bi.w;
      __builtin_nontemporal_store(o, &out4[g]);
      acc4[g] = make_float4(0.f, 0.f, 0.f, 0.f);   // fused re-zero
    }

    if (it + 1 < kRPB && r + 1 < B) {
      BAR_LDS(); // zeros + this row's acc reads done before next scatter
    }
  }
}

}  // namespace

extern "C" void kernel_launch(void* const* d_in, const int* in_sizes, int n_in,
                              void* d_out, int out_size, void* d_ws, size_t ws_size,
                              hipStream_t stream) {
  const float* x    = (const float*)d_in[0];   // (2048, 16384)
  const float* dna  = (const float*)d_in[1];   // (56,)
  const float* bias = (const float*)d_in[2];   // (8192,)
  float* out = (float*)d_out;                  // (2048, 8192)
  int4* rec = (int4*)d_ws;                     // 1000 * 16B scratch

  fractal_chaos<<<(kNP * 8 + 255) / 256, 256, 0, stream>>>(dna, rec);

  const int B = in_sizes[0] / kW;              // 2048
  fractal_apply<<<(B + kRPB - 1) / kRPB, 1024, 0, stream>>>(x, bias, rec,
                                                            out, B);
}

// Round 14
// 46.759 us; speedup vs baseline: 1.1274x; 1.1274x over previous
//
#include <hip/hip_runtime.h>
#include <stdint.h>

// ---------------------------------------------------------------------------
// FractalLinear: IFS chaos game (JAX threefry-exact) + bilinear gather/scatter
// Round 14: TLP-overlap apply. 1 row/block x 2048 blocks x 256 thr,
// 32KB LDS acc -> 5 blocks/CU (vs 2 in R12). Five desynchronized blocks
// per CU keep the fetch pipe (scattered gather) and write pipe (NT stream
// out) busy simultaneously -- no intra-block pipelining needed.
// Program-order rule learned in R13: gather loads must issue BEFORE any
// VMEM stores (vmcnt is issue-ordered; loads stuck behind store acks).
// LDS-only barriers (no vmcnt drain) kept from R12.
// Evidence: R12 42.3us best; depth-1 prefetch covers HBM latency; all
// byte-count / sort / hotspot / split theories refuted in R6-R11.
// ---------------------------------------------------------------------------
#ifndef PRNG_PARTITIONABLE
#define PRNG_PARTITIONABLE 1
#endif

namespace {

constexpr int kH  = 8192;
constexpr int kW  = 16384;
constexpr int kNT = 8;
constexpr int kNP = 1000;
constexpr int kCI = 10;

typedef float floatx4 __attribute__((ext_vector_type(4)));  // nontemporal-OK

// Raw barrier: wait only on LDS ops; global loads/stores stay in flight.
#define BAR_LDS() asm volatile("s_waitcnt lgkmcnt(0)\n\ts_barrier" ::: "memory")

__device__ __forceinline__ uint32_t rotl32(uint32_t x, int n) {
  return (x << n) | (x >> (32 - n));
}

// Threefry-2x32, 20 rounds (Random123 / JAX convention).
__device__ void threefry2x32(uint32_t k0, uint32_t k1, uint32_t c0, uint32_t c1,
                             uint32_t& o0, uint32_t& o1) {
  const uint32_t ks2 = k0 ^ k1 ^ 0x1BD11BDAu;
  uint32_t x0 = c0 + k0, x1 = c1 + k1;
#define TF_R(r) { x0 += x1; x1 = rotl32(x1, (r)); x1 ^= x0; }
  TF_R(13) TF_R(15) TF_R(26) TF_R(6)
  x0 += k1;  x1 += ks2 + 1u;
  TF_R(17) TF_R(29) TF_R(16) TF_R(24)
  x0 += ks2; x1 += k0 + 2u;
  TF_R(13) TF_R(15) TF_R(26) TF_R(6)
  x0 += k0;  x1 += k1 + 3u;
  TF_R(17) TF_R(29) TF_R(16) TF_R(24)
  x0 += k1;  x1 += ks2 + 4u;
  TF_R(13) TF_R(15) TF_R(26) TF_R(6)
  x0 += ks2; x1 += k0 + 5u;
#undef TF_R
  o0 = x0; o1 = x1;
}

__device__ __forceinline__ uint32_t random_bits32(uint32_t k0, uint32_t k1,
                                                  uint32_t i, uint32_t size) {
#if PRNG_PARTITIONABLE
  uint32_t o0, o1;
  threefry2x32(k0, k1, 0u /* hi(i) */, i, o0, o1);
  (void)size;
  return o0 ^ o1;
#else
  const uint32_t half = size / 2u;
  const uint32_t j = (i < half) ? i : (i - half);
  uint32_t o0, o1;
  threefry2x32(k0, k1, j, j + half, o0, o1);
  return (i < half) ? o0 : o1;
#endif
}

__device__ __forceinline__ float u01(uint32_t bits) {
  return __uint_as_float((bits >> 9) | 0x3f800000u) - 1.0f;
}

// x86 cvttss2si semantics: out-of-range / NaN -> INT_MIN (matches CPU-ref).
__device__ __forceinline__ int cvt_f32_i32_x86(float v) {
  if (!(v >= -2147483648.0f && v < 2147483648.0f)) return (int)0x80000000;
  return (int)v;
}

// ---------------------------------------------------------------------------
// Kernel 1: chaos game, 8 lanes per point (one transform each).
// ---------------------------------------------------------------------------
__global__ __launch_bounds__(256) void fractal_chaos(
    const float* __restrict__ dna, int4* __restrict__ rec) {
  const int gid  = blockIdx.x * blockDim.x + threadIdx.x;
  const int n    = gid >> 3;
  const int lane = gid & 7;
  if (n >= kNP) return;

  uint32_t kp0, kp1, kg0, kg1;
#if PRNG_PARTITIONABLE
  threefry2x32(0u, 1u, 0u, 0u, kp0, kp1);
  threefry2x32(0u, 1u, 0u, 1u, kg0, kg1);
#else
  uint32_t a0, a1, b0, b1;
  threefry2x32(0u, 1u, 0u, 2u, a0, a1);
  threefry2x32(0u, 1u, 1u, 3u, b0, b1);
  kp0 = a0; kp1 = b0; kg0 = a1; kg1 = b1;
#endif

  const float A  = dna[lane * 7 + 0], Bb = dna[lane * 7 + 1];
  const float C  = dna[lane * 7 + 2], D  = dna[lane * 7 + 3];
  const float E  = dna[lane * 7 + 4], F  = dna[lane * 7 + 5];
  const float P  = dna[lane * 7 + 6];

  float z[kCI];
  #pragma unroll
  for (int i = 0; i < kCI; ++i) {
    uint32_t ki0, ki1;
    threefry2x32(kg0, kg1, 0u, (uint32_t)i, ki0, ki1);   // fold_in(kg, i)
    const uint32_t bb = random_bits32(ki0, ki1, (uint32_t)(n * kNT + lane),
                                      (uint32_t)(kNP * kNT));
    const float u = fmaxf(u01(bb), 1.17549435e-38f);
    const float g = -logf(-logf(u));
    z[i] = P + g;
  }

  const uint32_t bx = random_bits32(kp0, kp1, (uint32_t)(2 * n),     2u * kNP);
  const uint32_t by = random_bits32(kp0, kp1, (uint32_t)(2 * n + 1), 2u * kNP);
  float px = u01(bx) * 2.0f - 1.0f;
  float py = u01(by) * 2.0f - 1.0f;

  #pragma unroll
  for (int i = 0; i < kCI; ++i) {
    // argmax over the 8 lanes, first-index tiebreak (matches jnp.argmax)
    float zb = z[i];
    int   bt = lane;
    #pragma unroll
    for (int m = 1; m < 8; m <<= 1) {
      const float zo = __shfl_xor(zb, m, 8);
      const int   to = __shfl_xor(bt, m, 8);
      if (zo > zb || (zo == zb && to < bt)) { zb = zo; bt = to; }
    }
    const float A_ = __shfl(A,  bt, 8), B_ = __shfl(Bb, bt, 8);
    const float C_ = __shfl(C,  bt, 8), D_ = __shfl(D,  bt, 8);
    const float E_ = __shfl(E,  bt, 8), F_ = __shfl(F,  bt, 8);
    const float nx = A_ * px + B_ * py + E_;
    const float ny = C_ * px + D_ * py + F_;
    px = nx; py = ny;
  }

  if (lane == 0) {
    const float xc = ((px + 1.0f) * 0.5f) * (float)(kW - 1);
    const float yc = ((py + 1.0f) * 0.5f) * (float)(kH - 1);
    int xl = cvt_f32_i32_x86(floorf(xc));
    int yl = cvt_f32_i32_x86(floorf(yc));
    xl = min(max(xl, 0), kW - 2);
    yl = min(max(yl, 0), kH - 2);
    const float xw = xc - (float)xl;   // NOT clipped (matches reference)
    const float yw = yc - (float)yl;
    rec[n] = make_int4(xl, __float_as_int(xw), yl, __float_as_int(yw));
  }
}

// ---------------------------------------------------------------------------
// Kernel 2: one row per block, 256 threads, 32KB LDS -> 5 blocks/CU.
// Loads first, LDS zero (lgkm only), scatter, epilogue. LDS-only barriers.
// ---------------------------------------------------------------------------
__global__ __launch_bounds__(256) void fractal_apply(
    const float* __restrict__ x, const float* __restrict__ bias,
    const int4* __restrict__ rec, float* __restrict__ out) {
  __shared__ __align__(16) float acc[kH];        // 32 KB
  const int tid = threadIdx.x;
  const int b   = blockIdx.x;
  const float* __restrict__ xrow = x + (size_t)b * kW;

  // point records (4 per thread) -- issue before everything else
  int4 r[4];
  #pragma unroll
  for (int j = 0; j < 4; ++j) {
    const int n = tid + j * 256;
    if (n < kNP) r[j] = rec[n];
  }

  // scattered gather loads (no VMEM stores issued yet -> clean vmcnt waits)
  float v0[4], v1[4];
  #pragma unroll
  for (int j = 0; j < 4; ++j) {
    const int n = tid + j * 256;
    if (n < kNP) {
      v0[j] = xrow[r[j].x];
      v1[j] = xrow[r[j].x + 1];
    }
  }

  // zero acc (LDS stores: lgkmcnt, not vmcnt -- overlaps the gathers)
  float4* acc4 = reinterpret_cast<float4*>(acc);
  #pragma unroll
  for (int j = 0; j < 8; ++j)
    acc4[tid + j * 256] = make_float4(0.f, 0.f, 0.f, 0.f);

  BAR_LDS();   // zeros visible; gather loads still in flight

  // scatter: vmcnt waits release each pair as it lands
  #pragma unroll
  for (int j = 0; j < 4; ++j) {
    const int n = tid + j * 256;
    if (n < kNP) {
      const float xw = __int_as_float(r[j].y);
      const float yw = __int_as_float(r[j].w);
      const float xv = v0[j] * (1.0f - xw) + v1[j] * xw;
      atomicAdd(&acc[r[j].z],     xv * (1.0f - yw));
      atomicAdd(&acc[r[j].z + 1], xv * yw);
    }
  }

  BAR_LDS();   // all scatters visible

  // epilogue: out = acc/1000 + bias, full-line nontemporal stores
  const floatx4* __restrict__ bias4 = reinterpret_cast<const floatx4*>(bias);
  floatx4* __restrict__ out4 = reinterpret_cast<floatx4*>(out + (size_t)b * kH);
  #pragma unroll
  for (int j = 0; j < 8; ++j) {
    const int g = tid + j * 256;
    const float4 a  = acc4[g];
    const floatx4 bi = bias4[g];
    floatx4 o;
    o.x = a.x / 1000.0f + bi.x;
    o.y = a.y / 1000.0f + bi.y;
    o.z = a.z / 1000.0f + bi.z;
    o.w = a.w / 1000.0f + bi.w;
    __builtin_nontemporal_store(o, &out4[g]);
  }
}

}  // namespace

extern "C" void kernel_launch(void* const* d_in, const int* in_sizes, int n_in,
                              void* d_out, int out_size, void* d_ws, size_t ws_size,
                              hipStream_t stream) {
  const float* x    = (const float*)d_in[0];   // (2048, 16384)
  const float* dna  = (const float*)d_in[1];   // (56,)
  const float* bias = (const float*)d_in[2];   // (8192,)
  float* out = (float*)d_out;                  // (2048, 8192)
  int4* rec = (int4*)d_ws;                     // 1000 * 16B scratch

  fractal_chaos<<<(kNP * 8 + 255) / 256, 256, 0, stream>>>(dna, rec);

  const int B = in_sizes[0] / kW;              // 2048
  fractal_apply<<<B, 256, 0, stream>>>(x, bias, rec, out);
}

// Round 15
// 43.732 us; speedup vs baseline: 1.2054x; 1.0692x over previous
//
#include <hip/hip_runtime.h>
#include <stdint.h>

// ---------------------------------------------------------------------------
// FractalLinear: IFS chaos game (JAX threefry-exact) + bilinear gather/scatter
// Round 15 = R12 pipelining x R14 concurrency:
//   512 thr/block, 32KB LDS acc, kRPB=2 -> 1024 blocks = 4 blocks/CU
//   (vs R12's 2), 32 waves/CU = max occupancy. Per row: scatter(cur) ->
//   issue next-row gathers (BEFORE epilogue stores; vmcnt is issue-ordered,
//   R13 lesson) -> LDS-only barrier -> epilogue (acc+bias, NT store, fused
//   re-zero) -> LDS-only barrier. No vmcnt drain anywhere in the loop.
//   Taps (xl, xl+1) loaded as one 8B floatx2 -> half the scattered requests.
// Evidence: R12 42.3us (pipelined, 2 blk/CU) > R14 46.8 (5 blk/CU, no pipe)
// > R13 52.7 (loads behind stores). Byte floor ~115MB ~ 18-23us mixed.
// ---------------------------------------------------------------------------
#ifndef PRNG_PARTITIONABLE
#define PRNG_PARTITIONABLE 1
#endif

namespace {

constexpr int kH  = 8192;
constexpr int kW  = 16384;
constexpr int kNT = 8;
constexpr int kNP = 1000;
constexpr int kCI = 10;
constexpr int kTh  = 512;        // threads per apply block
constexpr int kRPB = 2;          // rows per apply block (pipeline depth)

typedef float floatx4 __attribute__((ext_vector_type(4)));  // nontemporal-OK
typedef float floatx2 __attribute__((ext_vector_type(2), aligned(4)));

// Raw barrier: wait only on LDS ops; global loads/stores stay in flight.
// (__syncthreads emits s_waitcnt vmcnt(0) lgkmcnt(0) before s_barrier.)
#define BAR_LDS() asm volatile("s_waitcnt lgkmcnt(0)\n\ts_barrier" ::: "memory")

__device__ __forceinline__ uint32_t rotl32(uint32_t x, int n) {
  return (x << n) | (x >> (32 - n));
}

// Threefry-2x32, 20 rounds (Random123 / JAX convention).
__device__ void threefry2x32(uint32_t k0, uint32_t k1, uint32_t c0, uint32_t c1,
                             uint32_t& o0, uint32_t& o1) {
  const uint32_t ks2 = k0 ^ k1 ^ 0x1BD11BDAu;
  uint32_t x0 = c0 + k0, x1 = c1 + k1;
#define TF_R(r) { x0 += x1; x1 = rotl32(x1, (r)); x1 ^= x0; }
  TF_R(13) TF_R(15) TF_R(26) TF_R(6)
  x0 += k1;  x1 += ks2 + 1u;
  TF_R(17) TF_R(29) TF_R(16) TF_R(24)
  x0 += ks2; x1 += k0 + 2u;
  TF_R(13) TF_R(15) TF_R(26) TF_R(6)
  x0 += k0;  x1 += k1 + 3u;
  TF_R(17) TF_R(29) TF_R(16) TF_R(24)
  x0 += k1;  x1 += ks2 + 4u;
  TF_R(13) TF_R(15) TF_R(26) TF_R(6)
  x0 += ks2; x1 += k0 + 5u;
#undef TF_R
  o0 = x0; o1 = x1;
}

__device__ __forceinline__ uint32_t random_bits32(uint32_t k0, uint32_t k1,
                                                  uint32_t i, uint32_t size) {
#if PRNG_PARTITIONABLE
  uint32_t o0, o1;
  threefry2x32(k0, k1, 0u /* hi(i) */, i, o0, o1);
  (void)size;
  return o0 ^ o1;
#else
  const uint32_t half = size / 2u;
  const uint32_t j = (i < half) ? i : (i - half);
  uint32_t o0, o1;
  threefry2x32(k0, k1, j, j + half, o0, o1);
  return (i < half) ? o0 : o1;
#endif
}

__device__ __forceinline__ float u01(uint32_t bits) {
  return __uint_as_float((bits >> 9) | 0x3f800000u) - 1.0f;
}

// x86 cvttss2si semantics: out-of-range / NaN -> INT_MIN (matches CPU-ref).
__device__ __forceinline__ int cvt_f32_i32_x86(float v) {
  if (!(v >= -2147483648.0f && v < 2147483648.0f)) return (int)0x80000000;
  return (int)v;
}

// ---------------------------------------------------------------------------
// Kernel 1: chaos game, 8 lanes per point (one transform each).
// ---------------------------------------------------------------------------
__global__ __launch_bounds__(256) void fractal_chaos(
    const float* __restrict__ dna, int4* __restrict__ rec) {
  const int gid  = blockIdx.x * blockDim.x + threadIdx.x;
  const int n    = gid >> 3;
  const int lane = gid & 7;
  if (n >= kNP) return;

  uint32_t kp0, kp1, kg0, kg1;
#if PRNG_PARTITIONABLE
  threefry2x32(0u, 1u, 0u, 0u, kp0, kp1);
  threefry2x32(0u, 1u, 0u, 1u, kg0, kg1);
#else
  uint32_t a0, a1, b0, b1;
  threefry2x32(0u, 1u, 0u, 2u, a0, a1);
  threefry2x32(0u, 1u, 1u, 3u, b0, b1);
  kp0 = a0; kp1 = b0; kg0 = a1; kg1 = b1;
#endif

  const float A  = dna[lane * 7 + 0], Bb = dna[lane * 7 + 1];
  const float C  = dna[lane * 7 + 2], D  = dna[lane * 7 + 3];
  const float E  = dna[lane * 7 + 4], F  = dna[lane * 7 + 5];
  const float P  = dna[lane * 7 + 6];

  float z[kCI];
  #pragma unroll
  for (int i = 0; i < kCI; ++i) {
    uint32_t ki0, ki1;
    threefry2x32(kg0, kg1, 0u, (uint32_t)i, ki0, ki1);   // fold_in(kg, i)
    const uint32_t bb = random_bits32(ki0, ki1, (uint32_t)(n * kNT + lane),
                                      (uint32_t)(kNP * kNT));
    const float u = fmaxf(u01(bb), 1.17549435e-38f);
    const float g = -logf(-logf(u));
    z[i] = P + g;
  }

  const uint32_t bx = random_bits32(kp0, kp1, (uint32_t)(2 * n),     2u * kNP);
  const uint32_t by = random_bits32(kp0, kp1, (uint32_t)(2 * n + 1), 2u * kNP);
  float px = u01(bx) * 2.0f - 1.0f;
  float py = u01(by) * 2.0f - 1.0f;

  #pragma unroll
  for (int i = 0; i < kCI; ++i) {
    // argmax over the 8 lanes, first-index tiebreak (matches jnp.argmax)
    float zb = z[i];
    int   bt = lane;
    #pragma unroll
    for (int m = 1; m < 8; m <<= 1) {
      const float zo = __shfl_xor(zb, m, 8);
      const int   to = __shfl_xor(bt, m, 8);
      if (zo > zb || (zo == zb && to < bt)) { zb = zo; bt = to; }
    }
    const float A_ = __shfl(A,  bt, 8), B_ = __shfl(Bb, bt, 8);
    const float C_ = __shfl(C,  bt, 8), D_ = __shfl(D,  bt, 8);
    const float E_ = __shfl(E,  bt, 8), F_ = __shfl(F,  bt, 8);
    const float nx = A_ * px + B_ * py + E_;
    const float ny = C_ * px + D_ * py + F_;
    px = nx; py = ny;
  }

  if (lane == 0) {
    const float xc = ((px + 1.0f) * 0.5f) * (float)(kW - 1);
    const float yc = ((py + 1.0f) * 0.5f) * (float)(kH - 1);
    int xl = cvt_f32_i32_x86(floorf(xc));
    int yl = cvt_f32_i32_x86(floorf(yc));
    xl = min(max(xl, 0), kW - 2);
    yl = min(max(yl, 0), kH - 2);
    const float xw = xc - (float)xl;   // NOT clipped (matches reference)
    const float yw = yc - (float)yl;
    rec[n] = make_int4(xl, __float_as_int(xw), yl, __float_as_int(yw));
  }
}

// ---------------------------------------------------------------------------
// Kernel 2: pipelined apply, 512 thr, 2 rows/block, 1024 blocks (4/CU).
// ---------------------------------------------------------------------------
__global__ __launch_bounds__(kTh) void fractal_apply(
    const float* __restrict__ x, const float* __restrict__ bias,
    const int4* __restrict__ rec, float* __restrict__ out, int B) {
  __shared__ __align__(16) float acc[kH];        // 32 KB -> 4 blocks/CU
  const int tid = threadIdx.x;
  const int r0  = blockIdx.x * kRPB;

  // point records: n1 = tid (always < 1000), n2 = tid + 512 (if < 1000)
  const bool h2 = (tid + kTh) < kNP;
  const int4 rr1 = rec[tid];
  int4 rr2 = make_int4(0, 0, 0, 0);
  if (h2) rr2 = rec[tid + kTh];

  const int   xl1 = rr1.x,  yl1 = rr1.z;
  const float xw1 = __int_as_float(rr1.y), yw1 = __int_as_float(rr1.w);
  const float xo1 = 1.0f - xw1, wo1 = 1.0f - yw1;
  const int   xl2 = rr2.x,  yl2 = rr2.z;
  const float xw2 = __int_as_float(rr2.y), yw2 = __int_as_float(rr2.w);
  const float xo2 = 1.0f - xw2, wo2 = 1.0f - yw2;

  // prologue: issue row r0's gathers (adjacent taps -> one 8B load each)
  const float* xrow = x + (size_t)r0 * kW;
  floatx2 t1 = *(const floatx2*)(xrow + xl1);
  floatx2 t2 = h2 ? *(const floatx2*)(xrow + xl2) : (floatx2)0.f;

  // zero acc (LDS only; overlaps the gathers): 8192/512 = 4 float4/thread
  float4* acc4 = reinterpret_cast<float4*>(acc);
  #pragma unroll
  for (int j = 0; j < 4; ++j)
    acc4[tid + j * kTh] = make_float4(0.f, 0.f, 0.f, 0.f);

  BAR_LDS();   // zeros visible; gather loads still in flight

  const floatx4* __restrict__ bias4 = reinterpret_cast<const floatx4*>(bias);

  #pragma unroll
  for (int it = 0; it < kRPB; ++it) {
    const int r = r0 + it;
    if (r >= B) break;                        // block-uniform, barrier-safe

    // scatter current row (vmcnt wait releases this row's loads only)
    {
      const float xv1 = t1.x * xo1 + t1.y * xw1;
      atomicAdd(&acc[yl1],     xv1 * wo1);
      atomicAdd(&acc[yl1 + 1], xv1 * yw1);
      if (h2) {
        const float xv2 = t2.x * xo2 + t2.y * xw2;
        atomicAdd(&acc[yl2],     xv2 * wo2);
        atomicAdd(&acc[yl2 + 1], xv2 * yw2);
      }
    }

    // issue next row's gathers NOW (before the epilogue's NT stores --
    // vmcnt is issue-ordered; loads must not queue behind store acks)
    if (it + 1 < kRPB && r + 1 < B) {
      const float* xn = x + (size_t)(r + 1) * kW;
      t1 = *(const floatx2*)(xn + xl1);
      if (h2) t2 = *(const floatx2*)(xn + xl2);
    }

    BAR_LDS();   // all scatters visible (lgkm only; VMEM stays in flight)

    // epilogue: out = acc/1000 + bias, NT store, fused re-zero
    floatx4* __restrict__ out4 =
        reinterpret_cast<floatx4*>(out + (size_t)r * kH);
    #pragma unroll
    for (int j = 0; j < 4; ++j) {
      const int g = tid + j * kTh;
      const float4 a  = acc4[g];
      const floatx4 bi = bias4[g];
      floatx4 o;
      o.x = a.x / 1000.0f + bi.x;
      o.y = a.y / 1000.0f + bi.y;
      o.z = a.z / 1000.0f + bi.z;
      o.w = a.w / 1000.0f + bi.w;
      __builtin_nontemporal_store(o, &out4[g]);
      acc4[g] = make_float4(0.f, 0.f, 0.f, 0.f);   // fused re-zero
    }

    if (it + 1 < kRPB && r + 1 < B) {
      BAR_LDS(); // zeros + acc reads done before next scatter
    }
  }
}

}  // namespace

extern "C" void kernel_launch(void* const* d_in, const int* in_sizes, int n_in,
                              void* d_out, int out_size, void* d_ws, size_t ws_size,
                              hipStream_t stream) {
  const float* x    = (const float*)d_in[0];   // (2048, 16384)
  const float* dna  = (const float*)d_in[1];   // (56,)
  const float* bias = (const float*)d_in[2];   // (8192,)
  float* out = (float*)d_out;                  // (2048, 8192)
  int4* rec = (int4*)d_ws;                     // 1000 * 16B scratch

  fractal_chaos<<<(kNP * 8 + 255) / 256, 256, 0, stream>>>(dna, rec);

  const int B = in_sizes[0] / kW;              // 2048
  fractal_apply<<<(B + kRPB - 1) / kRPB, kTh, 0, stream>>>(x, bias, rec,
                                                           out, B);
}

// Round 16
// 40.527 us; speedup vs baseline: 1.3008x; 1.0791x over previous
//
#include <hip/hip_runtime.h>
#include <stdint.h>

// ---------------------------------------------------------------------------
// FractalLinear: IFS chaos game (JAX threefry-exact) + bilinear gather/scatter
// Round 16 = R12 (best, 42.3us) + DOUBLE-BUFFERED LDS accumulator:
//   acc[2][8192] (64KB, still 2 blocks/CU -- R12 was thread-limited anyway).
//   Per row only ONE barrier: scatter(i+1)->accB overlaps epilogue(i)<-accA
//   at wave level. rezero(accA) in epilogue(i) is ordered before
//   scatter(i+2) by BAR(i+1). Fetch pipe and write pipe run concurrently
//   inside each block instead of alternating.
//   + floatx2 tap loads (one 8B request per point instead of two 4B).
//   + bias preloaded to registers: epilogue issues NO global loads (R13
//     lesson: loads queued after NT stores stall on store acks).
// Evidence: R12 42.3 (2-barrier pipe) > R15 43.7 (4 blk/CU) > R14 46.8 >
// R4 46.5 > R13 52.7. Aggregate ~3.1 TB/s on 115MB; byte floor ~18-25us.
// ---------------------------------------------------------------------------
#ifndef PRNG_PARTITIONABLE
#define PRNG_PARTITIONABLE 1
#endif

namespace {

constexpr int kH  = 8192;
constexpr int kW  = 16384;
constexpr int kNT = 8;
constexpr int kNP = 1000;
constexpr int kCI = 10;
constexpr int kTh  = 1024;       // threads per apply block
constexpr int kRPB = 4;          // rows per apply block -> 512 blocks, all resident

typedef float floatx4 __attribute__((ext_vector_type(4)));  // nontemporal-OK
typedef float floatx2 __attribute__((ext_vector_type(2), aligned(4)));

// Raw barrier: wait only on LDS ops; global loads/stores stay in flight.
// (__syncthreads emits s_waitcnt vmcnt(0) lgkmcnt(0) before s_barrier.)
#define BAR_LDS() asm volatile("s_waitcnt lgkmcnt(0)\n\ts_barrier" ::: "memory")

__device__ __forceinline__ uint32_t rotl32(uint32_t x, int n) {
  return (x << n) | (x >> (32 - n));
}

// Threefry-2x32, 20 rounds (Random123 / JAX convention).
__device__ void threefry2x32(uint32_t k0, uint32_t k1, uint32_t c0, uint32_t c1,
                             uint32_t& o0, uint32_t& o1) {
  const uint32_t ks2 = k0 ^ k1 ^ 0x1BD11BDAu;
  uint32_t x0 = c0 + k0, x1 = c1 + k1;
#define TF_R(r) { x0 += x1; x1 = rotl32(x1, (r)); x1 ^= x0; }
  TF_R(13) TF_R(15) TF_R(26) TF_R(6)
  x0 += k1;  x1 += ks2 + 1u;
  TF_R(17) TF_R(29) TF_R(16) TF_R(24)
  x0 += ks2; x1 += k0 + 2u;
  TF_R(13) TF_R(15) TF_R(26) TF_R(6)
  x0 += k0;  x1 += k1 + 3u;
  TF_R(17) TF_R(29) TF_R(16) TF_R(24)
  x0 += k1;  x1 += ks2 + 4u;
  TF_R(13) TF_R(15) TF_R(26) TF_R(6)
  x0 += ks2; x1 += k0 + 5u;
#undef TF_R
  o0 = x0; o1 = x1;
}

__device__ __forceinline__ uint32_t random_bits32(uint32_t k0, uint32_t k1,
                                                  uint32_t i, uint32_t size) {
#if PRNG_PARTITIONABLE
  uint32_t o0, o1;
  threefry2x32(k0, k1, 0u /* hi(i) */, i, o0, o1);
  (void)size;
  return o0 ^ o1;
#else
  const uint32_t half = size / 2u;
  const uint32_t j = (i < half) ? i : (i - half);
  uint32_t o0, o1;
  threefry2x32(k0, k1, j, j + half, o0, o1);
  return (i < half) ? o0 : o1;
#endif
}

__device__ __forceinline__ float u01(uint32_t bits) {
  return __uint_as_float((bits >> 9) | 0x3f800000u) - 1.0f;
}

// x86 cvttss2si semantics: out-of-range / NaN -> INT_MIN (matches CPU-ref).
__device__ __forceinline__ int cvt_f32_i32_x86(float v) {
  if (!(v >= -2147483648.0f && v < 2147483648.0f)) return (int)0x80000000;
  return (int)v;
}

// ---------------------------------------------------------------------------
// Kernel 1: chaos game, 8 lanes per point (one transform each).
// ---------------------------------------------------------------------------
__global__ __launch_bounds__(256) void fractal_chaos(
    const float* __restrict__ dna, int4* __restrict__ rec) {
  const int gid  = blockIdx.x * blockDim.x + threadIdx.x;
  const int n    = gid >> 3;
  const int lane = gid & 7;
  if (n >= kNP) return;

  uint32_t kp0, kp1, kg0, kg1;
#if PRNG_PARTITIONABLE
  threefry2x32(0u, 1u, 0u, 0u, kp0, kp1);
  threefry2x32(0u, 1u, 0u, 1u, kg0, kg1);
#else
  uint32_t a0, a1, b0, b1;
  threefry2x32(0u, 1u, 0u, 2u, a0, a1);
  threefry2x32(0u, 1u, 1u, 3u, b0, b1);
  kp0 = a0; kp1 = b0; kg0 = a1; kg1 = b1;
#endif

  const float A  = dna[lane * 7 + 0], Bb = dna[lane * 7 + 1];
  const float C  = dna[lane * 7 + 2], D  = dna[lane * 7 + 3];
  const float E  = dna[lane * 7 + 4], F  = dna[lane * 7 + 5];
  const float P  = dna[lane * 7 + 6];

  float z[kCI];
  #pragma unroll
  for (int i = 0; i < kCI; ++i) {
    uint32_t ki0, ki1;
    threefry2x32(kg0, kg1, 0u, (uint32_t)i, ki0, ki1);   // fold_in(kg, i)
    const uint32_t bb = random_bits32(ki0, ki1, (uint32_t)(n * kNT + lane),
                                      (uint32_t)(kNP * kNT));
    const float u = fmaxf(u01(bb), 1.17549435e-38f);
    const float g = -logf(-logf(u));
    z[i] = P + g;
  }

  const uint32_t bx = random_bits32(kp0, kp1, (uint32_t)(2 * n),     2u * kNP);
  const uint32_t by = random_bits32(kp0, kp1, (uint32_t)(2 * n + 1), 2u * kNP);
  float px = u01(bx) * 2.0f - 1.0f;
  float py = u01(by) * 2.0f - 1.0f;

  #pragma unroll
  for (int i = 0; i < kCI; ++i) {
    // argmax over the 8 lanes, first-index tiebreak (matches jnp.argmax)
    float zb = z[i];
    int   bt = lane;
    #pragma unroll
    for (int m = 1; m < 8; m <<= 1) {
      const float zo = __shfl_xor(zb, m, 8);
      const int   to = __shfl_xor(bt, m, 8);
      if (zo > zb || (zo == zb && to < bt)) { zb = zo; bt = to; }
    }
    const float A_ = __shfl(A,  bt, 8), B_ = __shfl(Bb, bt, 8);
    const float C_ = __shfl(C,  bt, 8), D_ = __shfl(D,  bt, 8);
    const float E_ = __shfl(E,  bt, 8), F_ = __shfl(F,  bt, 8);
    const float nx = A_ * px + B_ * py + E_;
    const float ny = C_ * px + D_ * py + F_;
    px = nx; py = ny;
  }

  if (lane == 0) {
    const float xc = ((px + 1.0f) * 0.5f) * (float)(kW - 1);
    const float yc = ((py + 1.0f) * 0.5f) * (float)(kH - 1);
    int xl = cvt_f32_i32_x86(floorf(xc));
    int yl = cvt_f32_i32_x86(floorf(yc));
    xl = min(max(xl, 0), kW - 2);
    yl = min(max(yl, 0), kH - 2);
    const float xw = xc - (float)xl;   // NOT clipped (matches reference)
    const float yw = yc - (float)yl;
    rec[n] = make_int4(xl, __float_as_int(xw), yl, __float_as_int(yw));
  }
}

// ---------------------------------------------------------------------------
// Kernel 2: double-buffered pipelined apply. 512 blocks x 1024 thr, 4 rows.
// Per row: scatter(cur)->acc[p] ; issue next-row taps ; BAR ;
//          epilogue: acc[p] + bias(reg) -> NT store, rezero acc[p].
// acc[p^1] is concurrently scatter-written by faster waves (safe: disjoint
// buffers); rezero(acc[p]) ordered before scatter(it+2) by the next BAR.
// ---------------------------------------------------------------------------
__global__ __launch_bounds__(kTh) void fractal_apply(
    const float* __restrict__ x, const float* __restrict__ bias,
    const int4* __restrict__ rec, float* __restrict__ out, int B) {
  __shared__ __align__(16) float acc[2][kH];     // 64 KB -> 2 blocks/CU
  const int tid = threadIdx.x;
  const int r0  = blockIdx.x * kRPB;

  // per-thread point record (threads 0..999)
  const bool hav = tid < kNP;
  int xl = 0, yl = 0;
  float xw = 0.f, yw = 0.f;
  if (hav) {
    const int4 rr = rec[tid];
    xl = rr.x; xw = __int_as_float(rr.y);
    yl = rr.z; yw = __int_as_float(rr.w);
  }
  const float xw0 = 1.0f - xw;
  const float w0  = 1.0f - yw;

  // prologue: issue row r0's gather (one 8B load) BEFORE any VMEM store
  floatx2 t = (floatx2)0.f;
  if (hav && r0 < B) t = *(const floatx2*)(x + (size_t)r0 * kW + xl);

  // preload bias into registers: epilogue will issue NO global loads
  const floatx4* __restrict__ bias4 = reinterpret_cast<const floatx4*>(bias);
  floatx4 breg[2];
  breg[0] = bias4[tid];
  breg[1] = bias4[tid + kTh];

  // zero both accumulators (LDS only; overlaps the gather + bias loads)
  float4* acc4 = reinterpret_cast<float4*>(&acc[0][0]);
  #pragma unroll
  for (int j = 0; j < 4; ++j)
    acc4[tid + j * kTh] = make_float4(0.f, 0.f, 0.f, 0.f);

  BAR_LDS();   // zeros visible; gather load still in flight

  #pragma unroll
  for (int it = 0; it < kRPB; ++it) {
    const int r = r0 + it;
    if (r >= B) break;                        // block-uniform, barrier-safe
    const int p = it & 1;

    // scatter current row into acc[p] (vmcnt releases this row's 8B load)
    if (hav) {
      const float xv = t.x * xw0 + t.y * xw;
      atomicAdd(&acc[p][yl],     xv * w0);
      atomicAdd(&acc[p][yl + 1], xv * yw);
    }

    // issue next row's gather NOW (before the epilogue's NT stores)
    if (hav && it + 1 < kRPB && r + 1 < B)
      t = *(const floatx2*)(x + (size_t)(r + 1) * kW + xl);

    BAR_LDS();   // scatters into acc[p] visible; VMEM stays in flight
                 // (also orders prior epilogue's rezero of acc[p^1])

    // epilogue: out = acc[p]/1000 + bias(reg), NT store, fused rezero.
    // Faster waves proceed into scatter(it+1) -> acc[p^1] concurrently.
    float4* accp = reinterpret_cast<float4*>(&acc[p][0]);
    floatx4* __restrict__ out4 =
        reinterpret_cast<floatx4*>(out + (size_t)r * kH);
    #pragma unroll
    for (int j = 0; j < 2; ++j) {
      const int g = tid + j * kTh;
      const float4 a = accp[g];
      floatx4 o;
      o.x = a.x / 1000.0f + breg[j].x;
      o.y = a.y / 1000.0f + breg[j].y;
      o.z = a.z / 1000.0f + breg[j].z;
      o.w = a.w / 1000.0f + breg[j].w;
      __builtin_nontemporal_store(o, &out4[g]);
      accp[g] = make_float4(0.f, 0.f, 0.f, 0.f);   // fused rezero
    }
    // NO second barrier: next iteration scatters into acc[p^1]; the rezero
    // of acc[p] completes (per-thread) before BAR(it+1), which orders it
    // against scatter(it+2)'s writes into acc[p].
  }
}

}  // namespace

extern "C" void kernel_launch(void* const* d_in, const int* in_sizes, int n_in,
                              void* d_out, int out_size, void* d_ws, size_t ws_size,
                              hipStream_t stream) {
  const float* x    = (const float*)d_in[0];   // (2048, 16384)
  const float* dna  = (const float*)d_in[1];   // (56,)
  const float* bias = (const float*)d_in[2];   // (8192,)
  float* out = (float*)d_out;                  // (2048, 8192)
  int4* rec = (int4*)d_ws;                     // 1000 * 16B scratch

  fractal_chaos<<<(kNP * 8 + 255) / 256, 256, 0, stream>>>(dna, rec);

  const int B = in_sizes[0] / kW;              // 2048
  fractal_apply<<<(B + kRPB - 1) / kRPB, kTh, 0, stream>>>(x, bias, rec,
                                                           out, B);
}